// Round 11
// baseline (39.347 us; speedup 1.0000x reference)
//
#include <hip/hip_runtime.h>
#include <math.h>

#define BATCH 4
#define NPTS  8000
#define NCH   256
#define GDIM  20            // 20^3 = 8000 cells, ~1 point/cell
#define NCELL (GDIM*GDIM*GDIM)
#define CELLH (1.0f/GDIM)
#define EPS   1e-5f

// ws layout (bytes):
//   starts : [B][NCELL+16] int @ 0       (128256, rounded to 131072)
//   psort  : [B][NPTS] float4  @ 131072  (512000) (x,y,z, bitcast(orig j))
// total: 643072 bytes
#define STRIDE_ST (NCELL + 16)
#define WS_STARTS 0
#define WS_PSORT  131072

__device__ __forceinline__ int cell_clamp(float v) {
  int c = (int)(v * (float)GDIM);
  return c < 0 ? 0 : (c > GDIM - 1 ? GDIM - 1 : c);
}

// One block per batch: LDS histogram -> shuffle-scan (3 barriers) -> global
// starts (+ sentinel) + scatter into psort via LDS cursors.
// Threads 0..999 own 8 cells each (1000*8 == NCELL).  (unchanged from R10)
__global__ __launch_bounds__(1024) void build_kernel(const float* __restrict__ points,
                                                     int* __restrict__ starts,
                                                     float4* __restrict__ psort) {
  __shared__ int lst[NCELL];
  __shared__ int wtot[16];
  const int t = threadIdx.x;
  const int b = blockIdx.x;
  if (t < 1000) {
#pragma unroll
    for (int k = 0; k < 8; ++k) lst[t * 8 + k] = 0;
  }
  __syncthreads();

  const float* pb = points + (size_t)b * NPTS * 3;
  float px[8], py[8], pz[8];
  int pc[8];
#pragma unroll
  for (int k = 0; k < 8; ++k) {
    const int j = t + k * 1024;
    pc[k] = -1;
    if (j < NPTS) {
      px[k] = pb[j * 3 + 0];
      py[k] = pb[j * 3 + 1];
      pz[k] = pb[j * 3 + 2];
      pc[k] = (cell_clamp(pz[k]) * GDIM + cell_clamp(py[k])) * GDIM + cell_clamp(px[k]);
      atomicAdd(&lst[pc[k]], 1);
    }
  }
  __syncthreads();

  int v[8];
  int sum = 0;
  if (t < 1000) {
#pragma unroll
    for (int k = 0; k < 8; ++k) {
      v[k] = lst[t * 8 + k];
      sum += v[k];
    }
  }
  const int lane = t & 63, wv = t >> 6;
  int incl = sum;
#pragma unroll
  for (int d = 1; d < 64; d <<= 1) {
    const int u = __shfl_up(incl, d);
    if (lane >= d) incl += u;
  }
  if (lane == 63) wtot[wv] = incl;
  __syncthreads();
  if (wv == 0) {
    int x = (lane < 16) ? wtot[lane] : 0;
#pragma unroll
    for (int d = 1; d < 16; d <<= 1) {
      const int u = __shfl_up(x, d);
      if (lane >= d) x += u;
    }
    if (lane < 16) wtot[lane] = x;
  }
  __syncthreads();
  const int base = incl - sum + (wv ? wtot[wv - 1] : 0);

  int* stg = starts + b * STRIDE_ST;
  if (t < 1000) {
    int run = base;
#pragma unroll
    for (int k = 0; k < 8; ++k) {
      stg[t * 8 + k] = run;
      lst[t * 8 + k] = run;  // own cells only: no race
      run += v[k];
    }
  }
  if (t == 0) stg[NCELL] = NPTS;  // sentinel: end of last cell
  __syncthreads();

  float4* psb = psort + (size_t)b * NPTS;
#pragma unroll
  for (int k = 0; k < 8; ++k) {
    if (pc[k] >= 0) {
      const int pos = atomicAdd(&lst[pc[k]], 1);
      psb[pos] = make_float4(px[k], py[k], pz[k], __int_as_float(t + k * 1024));
    }
  }
}

// Top-1-OTHER accumulation; key (max(d2,0), j) lexicographic == reference
// sort key + stable tie-break; self skipped via p != i in the compare.
// ONE 16B load per candidate (R9 lesson).
#define SCAN_RANGE(P0, P1)                                        \
  for (int p = (P0); p < (P1); ++p) {                             \
    const float4 P = ps[p];                                       \
    const float dot = xi * P.x + yi * P.y + zi * P.z;             \
    const float sqj = P.x * P.x + P.y * P.y + P.z * P.z;          \
    const float d2 = fmaxf((sqi + sqj) - 2.0f * dot, 0.0f);       \
    const int j = __float_as_int(P.w);                            \
    const bool lt = (p != i) &&                                   \
        ((d2 < b0) || (d2 == b0 && j < j0));                      \
    b0 = lt ? d2 : b0;                                            \
    j0 = lt ? j : j0;                                             \
  }

#define MERGE_XOR(MASK)                                           \
  {                                                               \
    const float ob = __shfl_xor(mb0, MASK);                       \
    const int oj = __shfl_xor(mj0, MASK);                         \
    const bool keep = (mb0 < ob) || (mb0 == ob && mj0 < oj);      \
    mb0 = keep ? mb0 : ob;                                        \
    mj0 = keep ? mj0 : oj;                                        \
  }

// ONE WAVE PER QUERY, zero barriers, zero LDS. 256 threads = 4 waves =
// 4 consecutive sorted queries. Per wave: issue self-row va load early;
// 125 box cells split 2/lane (per-cell ranges, ~2 candidates/lane, wave
// critical path ~ max Poisson(2) over 64 ~= 7); 6-step butterfly gives all
// lanes the NN; same wave gathers vc + writes out (64 lanes x float4 =
// 256 ch). Conservative (2h)^2 bound; rare shell fallback, 64-lane split.
__global__ __launch_bounds__(256, 8) void search_gather_kernel(
    const float4* __restrict__ psort, const int* __restrict__ starts,
    const float* __restrict__ preds, float* __restrict__ out) {
  const int t = threadIdx.x;
  const int b = blockIdx.y;
  const int wv = t >> 6;
  const int lane = t & 63;
  const int i = blockIdx.x * 4 + wv;  // 2000*4 == 8000 exact
  const int* stg = starts + b * STRIDE_ST;
  const float4* ps = psort + (size_t)b * NPTS;

  const float4 Q = ps[i];  // wave-uniform address -> broadcast
  const float xi = Q.x, yi = Q.y, zi = Q.z;
  const int qorig = __float_as_int(Q.w);
  const float sqi = xi * xi + yi * yi + zi * zi;  // same expr as reference

  // self-row load issued BEFORE the search: depends only on Q, hides under scan
  const float* predb = preds + (size_t)b * NPTS * NCH;
  const float4 va = ((const float4*)(predb + (size_t)qorig * NCH))[lane];

  const int cx = cell_clamp(xi), cy = cell_clamp(yi), cz = cell_clamp(zi);

  // ---- r<=2 box: 125 cells, lane takes cells {lane, lane+64} ----
  int lo0 = 0, hi0 = 0, lo1 = 0, hi1 = 0;
  {
    const int c = lane;  // 0..63, always < 125
    const int dz = c / 25 - 2;
    const int rem = c % 25;
    const int z = cz + dz, y = cy + rem / 5 - 2, x = cx + rem % 5 - 2;
    if ((unsigned)z < GDIM && (unsigned)y < GDIM && (unsigned)x < GDIM) {
      const int cid = (z * GDIM + y) * GDIM + x;
      lo0 = stg[cid];
      hi0 = stg[cid + 1];
    }
  }
  if (lane < 61) {  // cells 64..124
    const int c = lane + 64;
    const int dz = c / 25 - 2;
    const int rem = c % 25;
    const int z = cz + dz, y = cy + rem / 5 - 2, x = cx + rem % 5 - 2;
    if ((unsigned)z < GDIM && (unsigned)y < GDIM && (unsigned)x < GDIM) {
      const int cid = (z * GDIM + y) * GDIM + x;
      lo1 = stg[cid];
      hi1 = stg[cid + 1];
    }
  }

  float b0 = INFINITY;
  int j0 = -1;
  SCAN_RANGE(lo0, hi0)
  SCAN_RANGE(lo1, hi1)

  float mb0 = b0;
  int mj0 = j0;
  MERGE_XOR(1) MERGE_XOR(2) MERGE_XOR(4) MERGE_XOR(8) MERGE_XOR(16) MERGE_XOR(32)

  if (!(mb0 + EPS <= (2.0f * CELLH) * (2.0f * CELLH))) {
    // ---- rare fallback: expanding Chebyshev shells r>=3, 64-lane split ----
    for (int r = 3; r <= GDIM; ++r) {
      const int W = 2 * r + 1;
      for (int idx = lane; idx < W * W; idx += 64) {
        const int dz = idx / W - r;
        const int dy = idx % W - r;
        const int z = cz + dz, y = cy + dy;
        if ((unsigned)z >= GDIM || (unsigned)y >= GDIM) continue;
        const int rowbase = (z * GDIM + y) * GDIM;
        if (dz == -r || dz == r || dy == -r || dy == r) {
          const int xl = cx > r ? cx - r : 0;
          const int xh = cx < GDIM - 1 - r ? cx + r : GDIM - 1;
          const int lo = stg[rowbase + xl], hi = stg[rowbase + xh + 1];
          SCAN_RANGE(lo, hi)
        } else {
          if (cx - r >= 0) {
            const int lo = stg[rowbase + cx - r], hi = stg[rowbase + cx - r + 1];
            SCAN_RANGE(lo, hi)
          }
          if (cx + r <= GDIM - 1) {
            const int lo = stg[rowbase + cx + r], hi = stg[rowbase + cx + r + 1];
            SCAN_RANGE(lo, hi)
          }
        }
      }
      mb0 = b0; mj0 = j0;
      MERGE_XOR(1) MERGE_XOR(2) MERGE_XOR(4) MERGE_XOR(8) MERGE_XOR(16) MERGE_XOR(32)
      const float rb = (float)r * CELLH;
      if (mb0 + EPS <= rb * rb) break;
    }
  }

  // ---- gather + mean: same wave, no barrier ----
  const float4 vc = ((const float4*)(predb + (size_t)mj0 * NCH))[lane];
  float4 r;
  r.x = 0.5f * (va.x + vc.x);
  r.y = 0.5f * (va.y + vc.y);
  r.z = 0.5f * (va.z + vc.z);
  r.w = 0.5f * (va.w + vc.w);
  float* outb = out + (size_t)b * NPTS * NCH;
  ((float4*)(outb + (size_t)qorig * NCH))[lane] = r;
}

extern "C" void kernel_launch(void* const* d_in, const int* in_sizes, int n_in,
                              void* d_out, int out_size, void* d_ws, size_t ws_size,
                              hipStream_t stream) {
  const float* points = (const float*)d_in[0];
  const float* preds = (const float*)d_in[1];
  // d_in[2] (k_vector) unused: reference hardcodes k = 2.
  float* out = (float*)d_out;

  char* ws = (char*)d_ws;
  int* starts = (int*)(ws + WS_STARTS);
  float4* psort = (float4*)(ws + WS_PSORT);

  build_kernel<<<BATCH, 1024, 0, stream>>>(points, starts, psort);
  search_gather_kernel<<<dim3(NPTS / 4, BATCH), 256, 0, stream>>>(psort, starts, preds, out);
}

// Round 12
// 34.579 us; speedup vs baseline: 1.1379x; 1.1379x over previous
//
#include <hip/hip_runtime.h>
#include <math.h>

#define BATCH 4
#define NPTS  8000
#define NCH   256
#define GDIM  20            // 20^3 = 8000 cells, ~1 point/cell
#define NCELL (GDIM*GDIM*GDIM)
#define CELLH (1.0f/GDIM)
#define EPS   1e-5f

// ws layout (bytes):
//   starts : [B][NCELL+16] int @ 0       (128256, rounded to 131072)
//   psort  : [B][NPTS] float4  @ 131072  (512000) (x,y,z, bitcast(orig j))
// total: 643072 bytes
#define STRIDE_ST (NCELL + 16)
#define WS_STARTS 0
#define WS_PSORT  131072

__device__ __forceinline__ int cell_clamp(float v) {
  int c = (int)(v * (float)GDIM);
  return c < 0 ? 0 : (c > GDIM - 1 ? GDIM - 1 : c);
}

// One block per batch: LDS histogram -> shuffle-scan (3 barriers) -> global
// starts (+ sentinel) + scatter into psort via LDS cursors.
// Thread t handles points [t*8, t*8+8) loaded as 6 float4 (96B contiguous);
// threads 0..999 also own cells [t*8, t*8+8) for histogram/scan.
__global__ __launch_bounds__(1024) void build_kernel(const float* __restrict__ points,
                                                     int* __restrict__ starts,
                                                     float4* __restrict__ psort) {
  __shared__ int lst[NCELL];
  __shared__ int wtot[16];
  const int t = threadIdx.x;
  const int b = blockIdx.x;
  if (t < 1000) {
#pragma unroll
    for (int k = 0; k < 8; ++k) lst[t * 8 + k] = 0;
  }
  __syncthreads();

  const float* pb = points + (size_t)b * NPTS * 3;
  float px[8], py[8], pz[8];
  int pc[8];
  if (t < 1000) {
    const float4* pv = (const float4*)pb;  // 6000 float4s per batch
    const float4 a0 = pv[t * 6 + 0], a1 = pv[t * 6 + 1], a2 = pv[t * 6 + 2];
    const float4 a3 = pv[t * 6 + 3], a4 = pv[t * 6 + 4], a5 = pv[t * 6 + 5];
    px[0] = a0.x; py[0] = a0.y; pz[0] = a0.z;
    px[1] = a0.w; py[1] = a1.x; pz[1] = a1.y;
    px[2] = a1.z; py[2] = a1.w; pz[2] = a2.x;
    px[3] = a2.y; py[3] = a2.z; pz[3] = a2.w;
    px[4] = a3.x; py[4] = a3.y; pz[4] = a3.z;
    px[5] = a3.w; py[5] = a4.x; pz[5] = a4.y;
    px[6] = a4.z; py[6] = a4.w; pz[6] = a5.x;
    px[7] = a5.y; py[7] = a5.z; pz[7] = a5.w;
#pragma unroll
    for (int k = 0; k < 8; ++k) {
      pc[k] = (cell_clamp(pz[k]) * GDIM + cell_clamp(py[k])) * GDIM + cell_clamp(px[k]);
      atomicAdd(&lst[pc[k]], 1);
    }
  }
  __syncthreads();

  // per-thread sum of its 8 cells, then wave scan + 16-wave-total scan
  int v[8];
  int sum = 0;
  if (t < 1000) {
#pragma unroll
    for (int k = 0; k < 8; ++k) {
      v[k] = lst[t * 8 + k];
      sum += v[k];
    }
  }
  const int lane = t & 63, wv = t >> 6;
  int incl = sum;
#pragma unroll
  for (int d = 1; d < 64; d <<= 1) {
    const int u = __shfl_up(incl, d);
    if (lane >= d) incl += u;
  }
  if (lane == 63) wtot[wv] = incl;
  __syncthreads();
  if (wv == 0) {
    int x = (lane < 16) ? wtot[lane] : 0;
#pragma unroll
    for (int d = 1; d < 16; d <<= 1) {
      const int u = __shfl_up(x, d);
      if (lane >= d) x += u;
    }
    if (lane < 16) wtot[lane] = x;
  }
  __syncthreads();
  const int base = incl - sum + (wv ? wtot[wv - 1] : 0);

  int* stg = starts + b * STRIDE_ST;
  if (t < 1000) {
    int run = base;
#pragma unroll
    for (int k = 0; k < 8; ++k) {
      stg[t * 8 + k] = run;
      lst[t * 8 + k] = run;  // own cells only: no race
      run += v[k];
    }
  }
  if (t == 0) stg[NCELL] = NPTS;  // sentinel: end of last cell
  __syncthreads();

  // scatter (LDS cursors); psort.w carries bitcast original index
  float4* psb = psort + (size_t)b * NPTS;
  if (t < 1000) {
#pragma unroll
    for (int k = 0; k < 8; ++k) {
      const int pos = atomicAdd(&lst[pc[k]], 1);
      psb[pos] = make_float4(px[k], py[k], pz[k], __int_as_float(t * 8 + k));
    }
  }
}

// Top-1-OTHER accumulation; key (max(d2,0), j) lexicographic == reference
// sort key + stable tie-break; self skipped via p != i in the compare.
// ONE 16B load per candidate (R9 lesson). Rescanning a range is idempotent
// (identical (d2,j) loses the strict compare) -> stage-2 full-box rescan ok.
#define SCAN_RANGE(P0, P1)                                        \
  for (int p = (P0); p < (P1); ++p) {                             \
    const float4 P = ps[p];                                       \
    const float dot = xi * P.x + yi * P.y + zi * P.z;             \
    const float sqj = P.x * P.x + P.y * P.y + P.z * P.z;          \
    const float d2 = fmaxf((sqi + sqj) - 2.0f * dot, 0.0f);       \
    const int j = __float_as_int(P.w);                            \
    const bool lt = (p != i) &&                                   \
        ((d2 < b0) || (d2 == b0 && j < j0));                      \
    b0 = lt ? d2 : b0;                                            \
    j0 = lt ? j : j0;                                             \
  }

#define MERGE_XOR(MASK)                                           \
  {                                                               \
    const float ob = __shfl_xor(mb0, MASK);                       \
    const int oj = __shfl_xor(mj0, MASK);                         \
    const bool keep = (mb0 < ob) || (mb0 == ob && mj0 < oj);      \
    mb0 = keep ? mb0 : ob;                                        \
    mj0 = keep ? mj0 : oj;                                        \
  }

// Fused NN search + gather/mean, ZERO LDS / ZERO barriers.
// 256 threads = 16 sorted-order queries x 16 lanes. Stage 1: 3^3 box
// (27 cells, 2 cell-ranges/lane) -> merged bound h^2 passes ~95-97% of
// queries. Stage 2 (rare, block-coherent): full 5^3 box as 25 row-ranges
// (idempotent rescan). Stage 3 (~1e-3): Chebyshev shells r>=3.
// Epilogue: query ql's result lives in wave ql/4 -> __shfl broadcast,
// same wave gathers both preds rows + writes out. No __syncthreads.
__global__ __launch_bounds__(256, 8) void search_gather_kernel(
    const float4* __restrict__ psort, const int* __restrict__ starts,
    const float* __restrict__ preds, float* __restrict__ out) {
  const int t = threadIdx.x;
  const int b = blockIdx.y;
  const int ql = t >> 4;  // 0..15
  const int s = t & 15;   // candidate split lane
  const int i = blockIdx.x * 16 + ql;  // 500*16 == 8000 exact
  const int* stg = starts + b * STRIDE_ST;
  const float4* ps = psort + (size_t)b * NPTS;
  const float4 Q = ps[i];
  const float xi = Q.x, yi = Q.y, zi = Q.z;
  const int qorig = __float_as_int(Q.w);
  const float sqi = xi * xi + yi * yi + zi * zi;  // same expr as reference
  const int cx = cell_clamp(xi), cy = cell_clamp(yi), cz = cell_clamp(zi);

  float b0 = INFINITY;
  int j0 = -1;

  // ---- stage 1: 3^3 box, 27 cells; lane s takes cells s and s+16 ----
  {
    int lo0 = 0, hi0 = 0, lo1 = 0, hi1 = 0;
    {
      const int c = s;  // 0..15, all < 27
      const int dz = c / 9 - 1;
      const int rem = c % 9;
      const int z = cz + dz, y = cy + rem / 3 - 1, x = cx + rem % 3 - 1;
      if ((unsigned)z < GDIM && (unsigned)y < GDIM && (unsigned)x < GDIM) {
        const int cid = (z * GDIM + y) * GDIM + x;
        lo0 = stg[cid];
        hi0 = stg[cid + 1];
      }
    }
    if (s < 11) {  // cells 16..26
      const int c = s + 16;
      const int dz = c / 9 - 1;
      const int rem = c % 9;
      const int z = cz + dz, y = cy + rem / 3 - 1, x = cx + rem % 3 - 1;
      if ((unsigned)z < GDIM && (unsigned)y < GDIM && (unsigned)x < GDIM) {
        const int cid = (z * GDIM + y) * GDIM + x;
        lo1 = stg[cid];
        hi1 = stg[cid + 1];
      }
    }
    SCAN_RANGE(lo0, hi0)
    SCAN_RANGE(lo1, hi1)
  }

  float mb0 = b0;
  int mj0 = j0;
  MERGE_XOR(1) MERGE_XOR(2) MERGE_XOR(4) MERGE_XOR(8)

  if (!(mb0 + EPS <= CELLH * CELLH)) {
    // ---- stage 2: full 5^3 box as 25 row-ranges (rows s and s+16) ----
    const int x0c = cx > 1 ? cx - 2 : 0;
    const int x1c = cx < GDIM - 2 ? cx + 2 : GDIM - 1;
    int rs[2], re[2];
#pragma unroll
    for (int rr = 0; rr < 2; ++rr) {
      const int kk = s + rr * 16;
      int lo = 0, hi = 0;
      if (kk < 25) {
        const int z = cz + kk / 5 - 2;
        const int y = cy + kk % 5 - 2;
        if ((unsigned)z < GDIM && (unsigned)y < GDIM) {
          const int rowbase = (z * GDIM + y) * GDIM;
          lo = stg[rowbase + x0c];
          hi = stg[rowbase + x1c + 1];  // sentinel covers == NCELL
        }
      }
      rs[rr] = lo;
      re[rr] = hi;
    }
#pragma unroll
    for (int rr = 0; rr < 2; ++rr) { SCAN_RANGE(rs[rr], re[rr]) }

    mb0 = b0; mj0 = j0;
    MERGE_XOR(1) MERGE_XOR(2) MERGE_XOR(4) MERGE_XOR(8)

    if (!(mb0 + EPS <= (2.0f * CELLH) * (2.0f * CELLH))) {
      // ---- stage 3: expanding Chebyshev shells r>=3, row-range form ----
      for (int r = 3; r <= GDIM; ++r) {
        const int W = 2 * r + 1;
        for (int idx = s; idx < W * W; idx += 16) {
          const int dz = idx / W - r;
          const int dy = idx % W - r;
          const int z = cz + dz, y = cy + dy;
          if ((unsigned)z >= GDIM || (unsigned)y >= GDIM) continue;
          const int rowbase = (z * GDIM + y) * GDIM;
          if (dz == -r || dz == r || dy == -r || dy == r) {
            const int xl = cx > r ? cx - r : 0;
            const int xh = cx < GDIM - 1 - r ? cx + r : GDIM - 1;
            const int lo = stg[rowbase + xl], hi = stg[rowbase + xh + 1];
            SCAN_RANGE(lo, hi)
          } else {
            if (cx - r >= 0) {
              const int lo = stg[rowbase + cx - r], hi = stg[rowbase + cx - r + 1];
              SCAN_RANGE(lo, hi)
            }
            if (cx + r <= GDIM - 1) {
              const int lo = stg[rowbase + cx + r], hi = stg[rowbase + cx + r + 1];
              SCAN_RANGE(lo, hi)
            }
          }
        }
        mb0 = b0; mj0 = j0;
        MERGE_XOR(1) MERGE_XOR(2) MERGE_XOR(4) MERGE_XOR(8)
        const float rb = (float)r * CELLH;
        if (mb0 + EPS <= rb * rb) break;
      }
    }
  }

  // ---- epilogue: wave w owns queries 4w..4w+3; shfl-broadcast, no LDS ----
  const int lane = t & 63;
  const float* predb = preds + (size_t)b * NPTS * NCH;
  float* outb = out + (size_t)b * NPTS * NCH;
#pragma unroll
  for (int k = 0; k < 4; ++k) {
    const int c = __shfl(mj0, k * 16);
    const int qo = __shfl(qorig, k * 16);
    const float4 va = ((const float4*)(predb + (size_t)qo * NCH))[lane];
    const float4 vc = ((const float4*)(predb + (size_t)c * NCH))[lane];
    float4 r;
    r.x = 0.5f * (va.x + vc.x);
    r.y = 0.5f * (va.y + vc.y);
    r.z = 0.5f * (va.z + vc.z);
    r.w = 0.5f * (va.w + vc.w);
    ((float4*)(outb + (size_t)qo * NCH))[lane] = r;
  }
}

extern "C" void kernel_launch(void* const* d_in, const int* in_sizes, int n_in,
                              void* d_out, int out_size, void* d_ws, size_t ws_size,
                              hipStream_t stream) {
  const float* points = (const float*)d_in[0];
  const float* preds = (const float*)d_in[1];
  // d_in[2] (k_vector) unused: reference hardcodes k = 2.
  float* out = (float*)d_out;

  char* ws = (char*)d_ws;
  int* starts = (int*)(ws + WS_STARTS);
  float4* psort = (float4*)(ws + WS_PSORT);

  build_kernel<<<BATCH, 1024, 0, stream>>>(points, starts, psort);
  search_gather_kernel<<<dim3(NPTS / 16, BATCH), 256, 0, stream>>>(psort, starts, preds, out);
}